// Round 9
// baseline (182.543 us; speedup 1.0000x reference)
//
#include <hip/hip_runtime.h>
#include <hip/hip_bf16.h>
#include <math.h>

typedef unsigned int uint;
typedef unsigned short ushort;

using short8 = __attribute__((ext_vector_type(8))) short;
using f32x4  = __attribute__((ext_vector_type(4))) float;

#define BT      65536
#define HID     512
#define IN_DIM  594
#define TRUNK   256
#define BINS    20
#define NCOMBO  320

#define WT_P_SZ (19*16*64*8)
#define RP_SZ   (16*64*8)
#define WA_P_SZ (8*20*64*8)

__device__ inline ushort f2bf(float f) {
    uint u = __float_as_uint(f);
    return (ushort)((u + 0x7fffu + ((u >> 16) & 1u)) >> 16);   // RNE
}

// packed f32x2 -> bf16x2; compiler emits v_cvt_pk_bf16_f32 (RNE on gfx950)
__device__ inline uint pk2(float lo, float hi) {
    union { __hip_bfloat162 b; uint u; } cv;
    cv.b = __float22bfloat162_rn(float2{lo, hi});
    return cv.u;
}
__device__ inline short8 cvt8pk(float4 a, float4 b) {
    union { uint4 t; short8 s; } cv;
    cv.t.x = pk2(a.x, a.y);
    cv.t.y = pk2(a.z, a.w);
    cv.t.z = pk2(b.x, b.y);
    cv.t.w = pk2(b.z, b.w);
    return cv.s;
}

// ---------------------------------------------------------------------------
// Pack weights to bf16 MFMA B-fragment layout (verified R2-R7):
//   frag elem j, lane l, frag (kk,n): B[k][col], k=kk*32+(l>>4)*8+j, col=n*16+(l&15)
// ---------------------------------------------------------------------------
__global__ __launch_bounds__(64) void pack_all(
    const float* __restrict__ trunk_w, const float* __restrict__ router_w,
    const float* __restrict__ inst_base_w, const float* __restrict__ inst_base_b,
    const float* __restrict__ group_base_w, const float* __restrict__ group_base_b,
    const float* __restrict__ inst_exp_w, const float* __restrict__ inst_exp_b,
    const float* __restrict__ group_exp_w, const float* __restrict__ group_exp_b,
    ushort* __restrict__ WtP, ushort* __restrict__ RP,
    ushort* __restrict__ WaP, float* __restrict__ wbias)
{
    const int b = blockIdx.x, l = threadIdx.x;
    const int lr = l & 15, lg = l >> 4;
    if (b < 304) {                      // trunk: kk 0..18, n 0..15
        int kk = b >> 4, n = b & 15;
        int col = n * 16 + lr;
        ushort* dst = WtP + ((size_t)(kk * 16 + n) * 64 + l) * 8;
        #pragma unroll
        for (int j = 0; j < 8; ++j) {
            int k = kk * 32 + lg * 8 + j;
            dst[j] = (k < IN_DIM) ? f2bf(trunk_w[k * TRUNK + col]) : (ushort)0;
        }
    } else if (b < 320) {               // router: kk 0..15
        int kk = b - 304;
        ushort* dst = RP + ((size_t)(kk * 64 + l)) * 8;
        #pragma unroll
        for (int j = 0; j < 8; ++j) {
            int k = kk * 32 + lg * 8 + j;
            dst[j] = (lr < 7) ? f2bf(router_w[k * 7 + lr]) : (ushort)0;
        }
    } else if (b < 480) {               // heads: kk 0..7, n 0..19
        int b2 = b - 320, kk = b2 / 20, n = b2 % 20;
        int combo = n * 16 + lr;
        int h = combo / 160, rem = combo % 160, kb = rem >> 3, p = rem & 7;
        const float* bw = h ? group_base_w : inst_base_w;
        const float* ew = h ? group_exp_w  : inst_exp_w;
        ushort* dst = WaP + ((size_t)(kk * 20 + n) * 64 + l) * 8;
        #pragma unroll
        for (int j = 0; j < 8; ++j) {
            int k = kk * 32 + lg * 8 + j;
            float v = (p == 0) ? bw[k * BINS + kb]
                               : ew[((p - 1) * TRUNK + k) * BINS + kb];
            dst[j] = f2bf(v);
        }
    } else {                            // bias[320]
        for (int c = l; c < NCOMBO; c += 64) {
            int h = c / 160, rem = c % 160, kb = rem >> 3, p = rem & 7;
            const float* bb = h ? group_base_b : inst_base_b;
            const float* eb = h ? group_exp_b  : inst_exp_b;
            wbias[c] = (p == 0) ? bb[kb] : eb[(p - 1) * BINS + kb];
        }
    }
}

// ---------------------------------------------------------------------------
// Fused main: 64 tokens/block, 4 waves, 1024 blocks, ONE barrier total.
// Phase A: N-split trunk (wave w: N-frags 4w..4w+3, all 4 M-frags); A-frags
//          loaded per-lane DIRECTLY from global (L2-shared across waves);
//          router computed redundantly per wave for all 4 M-frags.
// Phase C: N-split heads (wave w: N-frags 5w..5w+4) -> head weights once/block.
// LDS: zs[64][256] bf16 swizzled (32 KB) ONLY.
// ---------------------------------------------------------------------------
__global__ __launch_bounds__(256, 2) void fused_mfma(
    const float* __restrict__ h_t, const float* __restrict__ a_t,
    const float* __restrict__ d_t, const float* __restrict__ age,
    const float* __restrict__ trunk_b, const float* __restrict__ router_b,
    const ushort* __restrict__ WtP, const ushort* __restrict__ RP,
    const ushort* __restrict__ WaP, const float* __restrict__ wbias,
    float* __restrict__ out)
{
    __shared__ alignas(16) ushort zs[64 * 256];   // 32 KB

    const int tid = threadIdx.x;
    const int l = tid & 63, w = tid >> 6;
    const int lr = l & 15, lg = l >> 4;
    const int block0 = blockIdx.x * 64;

    f32x4 acc[4][4];                 // [M-frag][N-frag]
    f32x4 accr[4];                   // router, all 4 M-frags (redundant per wave)
    #pragma unroll
    for (int mm = 0; mm < 4; ++mm) {
        accr[mm] = (f32x4){0.f,0.f,0.f,0.f};
        #pragma unroll
        for (int nn = 0; nn < 4; ++nn) acc[mm][nn] = (f32x4){0.f,0.f,0.f,0.f};
    }

    // ---- phase A: trunk (K=608) + router (K=512), direct-global A, no bar -
    #pragma unroll 2
    for (int kk = 0; kk < 16; ++kk) {               // h_t chunks
        short8 a[4];
        #pragma unroll
        for (int mm = 0; mm < 4; ++mm) {
            const float4* p = (const float4*)(h_t
                + (size_t)(block0 + mm * 16 + lr) * HID + kk * 32 + lg * 8);
            a[mm] = cvt8pk(p[0], p[1]);
        }
        short8 rb = *(const short8*)(RP + (size_t)kk * 512 + l * 8);
        accr[0] = __builtin_amdgcn_mfma_f32_16x16x32_bf16(a[0], rb, accr[0],0,0,0);
        accr[1] = __builtin_amdgcn_mfma_f32_16x16x32_bf16(a[1], rb, accr[1],0,0,0);
        accr[2] = __builtin_amdgcn_mfma_f32_16x16x32_bf16(a[2], rb, accr[2],0,0,0);
        accr[3] = __builtin_amdgcn_mfma_f32_16x16x32_bf16(a[3], rb, accr[3],0,0,0);
        const ushort* wp = WtP + ((size_t)kk * 16 + w * 4) * 512;
        #pragma unroll
        for (int nn = 0; nn < 4; ++nn) {
            short8 bq = *(const short8*)(wp + (size_t)nn * 512 + l * 8);
            acc[0][nn] = __builtin_amdgcn_mfma_f32_16x16x32_bf16(a[0], bq, acc[0][nn],0,0,0);
            acc[1][nn] = __builtin_amdgcn_mfma_f32_16x16x32_bf16(a[1], bq, acc[1][nn],0,0,0);
            acc[2][nn] = __builtin_amdgcn_mfma_f32_16x16x32_bf16(a[2], bq, acc[2][nn],0,0,0);
            acc[3][nn] = __builtin_amdgcn_mfma_f32_16x16x32_bf16(a[3], bq, acc[3][nn],0,0,0);
        }
    }
    #pragma unroll
    for (int kk = 16; kk < 18; ++kk) {              // a_t chunks (no router)
        short8 a[4];
        #pragma unroll
        for (int mm = 0; mm < 4; ++mm) {
            const float4* p = (const float4*)(a_t
                + (size_t)(block0 + mm * 16 + lr) * 64 + (kk - 16) * 32 + lg * 8);
            a[mm] = cvt8pk(p[0], p[1]);
        }
        const ushort* wp = WtP + ((size_t)kk * 16 + w * 4) * 512;
        #pragma unroll
        for (int nn = 0; nn < 4; ++nn) {
            short8 bq = *(const short8*)(wp + (size_t)nn * 512 + l * 8);
            acc[0][nn] = __builtin_amdgcn_mfma_f32_16x16x32_bf16(a[0], bq, acc[0][nn],0,0,0);
            acc[1][nn] = __builtin_amdgcn_mfma_f32_16x16x32_bf16(a[1], bq, acc[1][nn],0,0,0);
            acc[2][nn] = __builtin_amdgcn_mfma_f32_16x16x32_bf16(a[2], bq, acc[2][nn],0,0,0);
            acc[3][nn] = __builtin_amdgcn_mfma_f32_16x16x32_bf16(a[3], bq, acc[3][nn],0,0,0);
        }
    }
    {                                               // tail chunk kk=18: d_t/age/pad
        short8 a[4];
        #pragma unroll
        for (int mm = 0; mm < 4; ++mm) {
            size_t tok = block0 + mm * 16 + lr;
            float f[8];
            #pragma unroll
            for (int j = 0; j < 8; ++j) {
                int c = 576 + lg * 8 + j;
                float v;
                if (c < 578)      v = d_t[tok * 2 + (c - 576)];
                else if (c < 594) v = age[tok * 16 + (c - 578)];
                else              v = 0.f;
                f[j] = v;
            }
            a[mm] = cvt8pk(float4{f[0],f[1],f[2],f[3]}, float4{f[4],f[5],f[6],f[7]});
        }
        const ushort* wp = WtP + ((size_t)18 * 16 + w * 4) * 512;
        #pragma unroll
        for (int nn = 0; nn < 4; ++nn) {
            short8 bq = *(const short8*)(wp + (size_t)nn * 512 + l * 8);
            acc[0][nn] = __builtin_amdgcn_mfma_f32_16x16x32_bf16(a[0], bq, acc[0][nn],0,0,0);
            acc[1][nn] = __builtin_amdgcn_mfma_f32_16x16x32_bf16(a[1], bq, acc[1][nn],0,0,0);
            acc[2][nn] = __builtin_amdgcn_mfma_f32_16x16x32_bf16(a[2], bq, acc[2][nn],0,0,0);
            acc[3][nn] = __builtin_amdgcn_mfma_f32_16x16x32_bf16(a[3], bq, acc[3][nn],0,0,0);
        }
    }

    // ---- router softmax in registers (all 64 rows, per wave) --------------
    float pwv[4][4];
    {
        const float rb_l = (lr < 7) ? router_b[lr] : 0.f;
        #pragma unroll
        for (int mm = 0; mm < 4; ++mm)
        #pragma unroll
        for (int r = 0; r < 4; ++r) {
            float x = (lr < 7) ? (accr[mm][r] + rb_l) : -3.0e38f;
            float mx = x;
            mx = fmaxf(mx, __shfl_xor(mx, 1));
            mx = fmaxf(mx, __shfl_xor(mx, 2));
            mx = fmaxf(mx, __shfl_xor(mx, 4));
            mx = fmaxf(mx, __shfl_xor(mx, 8));
            float e = expf(x - mx);
            float s = e;
            s += __shfl_xor(s, 1);
            s += __shfl_xor(s, 2);
            s += __shfl_xor(s, 4);
            s += __shfl_xor(s, 8);
            pwv[mm][r] = e / s;
        }
    }

    // ---- epilogue: bias + exact GELU -> swizzled bf16 zs ------------------
    // wave w writes cols w*64..+63 for all 64 rows
    {
        char* zb = (char*)zs;
        #pragma unroll
        for (int nn = 0; nn < 4; ++nn) {
            int colbase = (w * 4 + nn) * 16 + lr;
            float tb = trunk_b[colbase];
            #pragma unroll
            for (int mm = 0; mm < 4; ++mm)
            #pragma unroll
            for (int r = 0; r < 4; ++r) {
                float v = acc[mm][nn][r] + tb;
                v = 0.5f * v * (1.f + erff(v * 0.70710678118654752f));
                int row  = mm * 16 + lg * 4 + r;
                int slot = (colbase >> 3) ^ (row & 7);
                *(ushort*)(zb + row * 512 + slot * 16 + (colbase & 7) * 2) = f2bf(v);
            }
        }
    }
    __syncthreads();   // the ONLY barrier: zs written N-split, read all-cols

    // ---- phase C: head GEMM, N-split: wave w N-frags 5w..5w+4, K=256 ------
    const char* zb = (const char*)zs;
    const int p8 = l & 7;
    const int csrc = (l & 48) | (p8 ? (p8 - 1) : 0);

    f32x4 acc2[4][5];
    #pragma unroll
    for (int mm = 0; mm < 4; ++mm)
    #pragma unroll
    for (int nn = 0; nn < 5; ++nn) acc2[mm][nn] = (f32x4){0.f,0.f,0.f,0.f};

    #pragma unroll
    for (int kk = 0; kk < 8; ++kk) {
        short8 a[4];
        #pragma unroll
        for (int mm = 0; mm < 4; ++mm) {
            int row = mm * 16 + lr;
            a[mm] = *(const short8*)(zb + row * 512 + (((kk * 4 + lg) ^ (row & 7)) << 4));
        }
        const ushort* wp = WaP + ((size_t)kk * 20 + w * 5) * 512;
        #pragma unroll
        for (int nn = 0; nn < 5; ++nn) {
            short8 bq = *(const short8*)(wp + (size_t)nn * 512 + l * 8);
            acc2[0][nn] = __builtin_amdgcn_mfma_f32_16x16x32_bf16(a[0], bq, acc2[0][nn],0,0,0);
            acc2[1][nn] = __builtin_amdgcn_mfma_f32_16x16x32_bf16(a[1], bq, acc2[1][nn],0,0,0);
            acc2[2][nn] = __builtin_amdgcn_mfma_f32_16x16x32_bf16(a[2], bq, acc2[2][nn],0,0,0);
            acc2[3][nn] = __builtin_amdgcn_mfma_f32_16x16x32_bf16(a[3], bq, acc2[3][nn],0,0,0);
        }
    }

    // ---- phase E: bias, phase-weighted 8-lane reduce, store ---------------
    {
        float cw[4][4];
        #pragma unroll
        for (int mm = 0; mm < 4; ++mm)
        #pragma unroll
        for (int r = 0; r < 4; ++r)
            cw[mm][r] = __shfl(pwv[mm][r], csrc);

        #pragma unroll
        for (int nn = 0; nn < 5; ++nn) {
            int combo = (w * 5 + nn) * 16 + lr;
            float wb = wbias[combo];
            int h = combo / 160, rem = combo % 160, kb = rem >> 3;
            #pragma unroll
            for (int mm = 0; mm < 4; ++mm)
            #pragma unroll
            for (int r = 0; r < 4; ++r) {
                float e = acc2[mm][nn][r] + wb;
                float val = (p8 ? cw[mm][r] : 1.0f) * e;
                val += __shfl_xor(val, 1);
                val += __shfl_xor(val, 2);
                val += __shfl_xor(val, 4);
                if (p8 == 0) {
                    size_t t = block0 + mm * 16 + lg * 4 + r;
                    out[(size_t)h * (BT * BINS) + t * BINS + kb] = val;
                }
            }
        }
    }
}

// ---------------------------------------------------------------------------
extern "C" void kernel_launch(void* const* d_in, const int* in_sizes, int n_in,
                              void* d_out, int out_size, void* d_ws, size_t ws_size,
                              hipStream_t stream) {
    const float* h_t          = (const float*)d_in[0];
    const float* a_t          = (const float*)d_in[1];
    const float* d_t          = (const float*)d_in[2];
    const float* age_embed    = (const float*)d_in[3];
    const float* trunk_w      = (const float*)d_in[4];
    const float* trunk_b      = (const float*)d_in[5];
    const float* inst_base_w  = (const float*)d_in[6];
    const float* inst_base_b  = (const float*)d_in[7];
    const float* group_base_w = (const float*)d_in[8];
    const float* group_base_b = (const float*)d_in[9];
    const float* inst_exp_w   = (const float*)d_in[10];
    const float* inst_exp_b   = (const float*)d_in[11];
    const float* group_exp_w  = (const float*)d_in[12];
    const float* group_exp_b  = (const float*)d_in[13];
    const float* router_w     = (const float*)d_in[14];
    const float* router_b     = (const float*)d_in[15];

    ushort* WtP   = (ushort*)d_ws;
    ushort* RP    = WtP + WT_P_SZ;
    ushort* WaP   = RP + RP_SZ;
    float*  wbias = (float*)(WaP + WA_P_SZ);

    pack_all<<<481, 64, 0, stream>>>(
        trunk_w, router_w,
        inst_base_w, inst_base_b, group_base_w, group_base_b,
        inst_exp_w, inst_exp_b, group_exp_w, group_exp_b,
        WtP, RP, WaP, wbias);

    fused_mfma<<<BT / 64, 256, 0, stream>>>(
        h_t, a_t, d_t, age_embed, trunk_b, router_b,
        WtP, RP, WaP, wbias, (float*)d_out);
}

// Round 10
// 106.819 us; speedup vs baseline: 1.7089x; 1.7089x over previous
//
#include <hip/hip_runtime.h>
#include <hip/hip_bf16.h>
#include <math.h>

typedef unsigned int uint;
typedef unsigned short ushort;

using short8 = __attribute__((ext_vector_type(8))) short;
using f32x4  = __attribute__((ext_vector_type(4))) float;

#define BT      65536
#define HID     512
#define IN_DIM  594
#define TRUNK   256
#define BINS    20
#define NCOMBO  320

#define WT_P_SZ (19*16*64*8)
#define RP_SZ   (16*64*8)
#define WA_P_SZ (8*20*64*8)

__device__ inline ushort f2bf(float f) {
    uint u = __float_as_uint(f);
    return (ushort)((u + 0x7fffu + ((u >> 16) & 1u)) >> 16);   // RNE
}

// packed f32x2 -> bf16x2; compiler emits v_cvt_pk_bf16_f32 (RNE)
__device__ inline uint pk2(float lo, float hi) {
    union { __hip_bfloat162 b; uint u; } cv;
    cv.b = __float22bfloat162_rn(float2{lo, hi});
    return cv.u;
}
__device__ inline short8 cvt8pk(float4 a, float4 b) {
    union { uint4 t; short8 s; } cv;
    cv.t.x = pk2(a.x, a.y);
    cv.t.y = pk2(a.z, a.w);
    cv.t.z = pk2(b.x, b.y);
    cv.t.w = pk2(b.z, b.w);
    return cv.s;
}

// ---------------------------------------------------------------------------
// Pack weights to bf16 MFMA B-fragment layout (verified R2-R9):
//   frag elem j, lane l, frag (kk,n): B[k][col], k=kk*32+(l>>4)*8+j, col=n*16+(l&15)
// ---------------------------------------------------------------------------
__global__ __launch_bounds__(64) void pack_all(
    const float* __restrict__ trunk_w, const float* __restrict__ router_w,
    const float* __restrict__ inst_base_w, const float* __restrict__ inst_base_b,
    const float* __restrict__ group_base_w, const float* __restrict__ group_base_b,
    const float* __restrict__ inst_exp_w, const float* __restrict__ inst_exp_b,
    const float* __restrict__ group_exp_w, const float* __restrict__ group_exp_b,
    ushort* __restrict__ WtP, ushort* __restrict__ RP,
    ushort* __restrict__ WaP, float* __restrict__ wbias)
{
    const int b = blockIdx.x, l = threadIdx.x;
    const int lr = l & 15, lg = l >> 4;
    if (b < 304) {                      // trunk: kk 0..18, n 0..15
        int kk = b >> 4, n = b & 15;
        int col = n * 16 + lr;
        ushort* dst = WtP + ((size_t)(kk * 16 + n) * 64 + l) * 8;
        #pragma unroll
        for (int j = 0; j < 8; ++j) {
            int k = kk * 32 + lg * 8 + j;
            dst[j] = (k < IN_DIM) ? f2bf(trunk_w[k * TRUNK + col]) : (ushort)0;
        }
    } else if (b < 320) {               // router: kk 0..15
        int kk = b - 304;
        ushort* dst = RP + ((size_t)(kk * 64 + l)) * 8;
        #pragma unroll
        for (int j = 0; j < 8; ++j) {
            int k = kk * 32 + lg * 8 + j;
            dst[j] = (lr < 7) ? f2bf(router_w[k * 7 + lr]) : (ushort)0;
        }
    } else if (b < 480) {               // heads: kk 0..7, n 0..19
        int b2 = b - 320, kk = b2 / 20, n = b2 % 20;
        int combo = n * 16 + lr;
        int h = combo / 160, rem = combo % 160, kb = rem >> 3, p = rem & 7;
        const float* bw = h ? group_base_w : inst_base_w;
        const float* ew = h ? group_exp_w  : inst_exp_w;
        ushort* dst = WaP + ((size_t)(kk * 20 + n) * 64 + l) * 8;
        #pragma unroll
        for (int j = 0; j < 8; ++j) {
            int k = kk * 32 + lg * 8 + j;
            float v = (p == 0) ? bw[k * BINS + kb]
                               : ew[((p - 1) * TRUNK + k) * BINS + kb];
            dst[j] = f2bf(v);
        }
    } else {                            // bias[320]
        for (int c = l; c < NCOMBO; c += 64) {
            int h = c / 160, rem = c % 160, kb = rem >> 3, p = rem & 7;
            const float* bb = h ? group_base_b : inst_base_b;
            const float* eb = h ? group_exp_b  : inst_exp_b;
            wbias[c] = (p == 0) ? bb[kb] : eb[(p - 1) * BINS + kb];
        }
    }
}

// ---------------------------------------------------------------------------
// Fused main (R5 geometry + depth-2 staging pipeline, T3/T4/T14):
// 128 tokens/block, 4 waves, 512 blocks (2 blocks/CU).
// Phase A: N-split trunk; x staged via xs[3] triple buffer. Per iter:
//   issue loads kk+2 -> MFMA xs[kk%3] -> cvt_pk+ds_write kk+1 (counted vmcnt,
//   kk+2 stays in flight) -> lgkmcnt(0) + RAW s_barrier (no vmcnt drain).
// Phase C: M-split heads with hf-split (exactly R5).
// LDS: zs[128][256] bf16 swizzled (64 KB); xs[3] = first 24 KB.
// ---------------------------------------------------------------------------
__global__ __launch_bounds__(256, 2) void fused_mfma(
    const float* __restrict__ h_t, const float* __restrict__ a_t,
    const float* __restrict__ d_t, const float* __restrict__ age,
    const float* __restrict__ trunk_b, const float* __restrict__ router_b,
    const ushort* __restrict__ WtP, const ushort* __restrict__ RP,
    const ushort* __restrict__ WaP, const float* __restrict__ wbias,
    float* __restrict__ out)
{
    __shared__ alignas(16) ushort zs[32768];   // 64 KB; xs[3] = first 12288 ushorts

    const int tid = threadIdx.x;
    const int l = tid & 63, w = tid >> 6;
    const int lr = l & 15, lg = l >> 4;
    const int block0 = blockIdx.x * 128;

    // staging map (R5, bank-clean): thread -> (row, 16-col half of 32-col chunk)
    const int srow = tid >> 1;
    const int half = tid & 1;
    const size_t stok = block0 + srow;

    ushort* xs = zs;   // xs[slot][frag mm][lane*8], slot stride 4096 ushorts

    f32x4 acc[8][4];                          // [M-frag][N-frag]
    f32x4 accr0 = (f32x4){0.f,0.f,0.f,0.f};  // router, M-frag 2w
    f32x4 accr1 = (f32x4){0.f,0.f,0.f,0.f};  // router, M-frag 2w+1
    #pragma unroll
    for (int mm = 0; mm < 8; ++mm)
    #pragma unroll
    for (int nn = 0; nn < 4; ++nn) acc[mm][nn] = (f32x4){0.f,0.f,0.f,0.f};

    auto stage_load = [&](int kk, float4* dst) {   // dst[4] = 16 floats
        if (kk < 16) {
            const float4* p = (const float4*)(h_t + stok * HID + kk * 32 + half * 16);
            dst[0]=p[0]; dst[1]=p[1]; dst[2]=p[2]; dst[3]=p[3];
        } else if (kk < 18) {
            const float4* p = (const float4*)(a_t + stok * 64 + (kk - 16) * 32 + half * 16);
            dst[0]=p[0]; dst[1]=p[1]; dst[2]=p[2]; dst[3]=p[3];
        } else {
            float* f = (float*)dst;
            #pragma unroll
            for (int j = 0; j < 16; ++j) {
                int c = 576 + half * 16 + j;
                float v;
                if (c < 578)      v = d_t[stok * 2 + (c - 576)];
                else if (c < 594) v = age[stok * 16 + (c - 578)];
                else              v = 0.f;
                f[j] = v;
            }
        }
    };
    auto stage_write = [&](int slot, const float4* ld) {
        short8 v0 = cvt8pk(ld[0], ld[1]);
        short8 v1 = cvt8pk(ld[2], ld[3]);
        ushort* dst = xs + slot * 4096
                      + (srow >> 4) * 512 + ((srow & 15) + half * 32) * 8;
        *(short8*)dst = v0;
        *(short8*)(dst + 128) = v1;     // lane + 16
    };

    auto mfma_chunk = [&](const ushort* xb, int kk, bool do_router) {
        short8 a[8];
        #pragma unroll
        for (int mm = 0; mm < 8; ++mm)
            a[mm] = *(const short8*)(xb + (mm * 64 + l) * 8);
        if (do_router) {
            short8 rb  = *(const short8*)(RP + (size_t)kk * 512 + l * 8);
            short8 ar0 = *(const short8*)(xb + ((2 * w + 0) * 64 + l) * 8);
            short8 ar1 = *(const short8*)(xb + ((2 * w + 1) * 64 + l) * 8);
            accr0 = __builtin_amdgcn_mfma_f32_16x16x32_bf16(ar0, rb, accr0, 0, 0, 0);
            accr1 = __builtin_amdgcn_mfma_f32_16x16x32_bf16(ar1, rb, accr1, 0, 0, 0);
        }
        const ushort* wp = WtP + ((size_t)kk * 16 + w * 4) * 512;
        #pragma unroll
        for (int nn = 0; nn < 4; ++nn) {
            short8 bq = *(const short8*)(wp + (size_t)nn * 512 + l * 8);
            acc[0][nn] = __builtin_amdgcn_mfma_f32_16x16x32_bf16(a[0], bq, acc[0][nn],0,0,0);
            acc[1][nn] = __builtin_amdgcn_mfma_f32_16x16x32_bf16(a[1], bq, acc[1][nn],0,0,0);
            acc[2][nn] = __builtin_amdgcn_mfma_f32_16x16x32_bf16(a[2], bq, acc[2][nn],0,0,0);
            acc[3][nn] = __builtin_amdgcn_mfma_f32_16x16x32_bf16(a[3], bq, acc[3][nn],0,0,0);
            acc[4][nn] = __builtin_amdgcn_mfma_f32_16x16x32_bf16(a[4], bq, acc[4][nn],0,0,0);
            acc[5][nn] = __builtin_amdgcn_mfma_f32_16x16x32_bf16(a[5], bq, acc[5][nn],0,0,0);
            acc[6][nn] = __builtin_amdgcn_mfma_f32_16x16x32_bf16(a[6], bq, acc[6][nn],0,0,0);
            acc[7][nn] = __builtin_amdgcn_mfma_f32_16x16x32_bf16(a[7], bq, acc[7][nn],0,0,0);
        }
    };

    // ---- phase A: trunk (K=608) + router (K=512), depth-2 pipeline --------
    {
        float4 rA[4], rB[4];
        stage_load(0, rA);
        stage_load(1, rB);           // stays in flight across the barrier
        stage_write(0, rA);
        asm volatile("s_waitcnt lgkmcnt(0)" ::: "memory");
        __builtin_amdgcn_s_barrier();

        #pragma unroll 1
        for (int kk = 0; kk < 19; ++kk) {
            float4 rC[4];
            if (kk + 2 < 19) stage_load(kk + 2, rC);     // issue 2 ahead
            mfma_chunk(xs + (kk % 3) * 4096, kk, kk < 16);
            if (kk + 1 < 19) stage_write((kk + 1) % 3, rB);  // counted vmcnt:
            // rC's loads are younger -> compiler waits only rB's, rC in flight
            asm volatile("s_waitcnt lgkmcnt(0)" ::: "memory");
            __builtin_amdgcn_s_barrier();                // NO vmcnt drain
            if (kk + 2 < 19) {
                rB[0] = rC[0]; rB[1] = rC[1]; rB[2] = rC[2]; rB[3] = rC[3];
            }
        }
    }

    // ---- router softmax in registers (rows w*32..+31) ---------------------
    float pwv[2][4];
    {
        const float rb_l = (lr < 7) ? router_b[lr] : 0.f;
        #pragma unroll
        for (int m = 0; m < 2; ++m)
        #pragma unroll
        for (int r = 0; r < 4; ++r) {
            float lv = (m == 0) ? accr0[r] : accr1[r];
            float x = (lr < 7) ? (lv + rb_l) : -3.0e38f;
            float mx = x;
            mx = fmaxf(mx, __shfl_xor(mx, 1));
            mx = fmaxf(mx, __shfl_xor(mx, 2));
            mx = fmaxf(mx, __shfl_xor(mx, 4));
            mx = fmaxf(mx, __shfl_xor(mx, 8));
            float e = expf(x - mx);
            float s = e;
            s += __shfl_xor(s, 1);
            s += __shfl_xor(s, 2);
            s += __shfl_xor(s, 4);
            s += __shfl_xor(s, 8);
            pwv[m][r] = e / s;
        }
    }

    // ---- epilogue: bias + exact GELU -> swizzled bf16 zs ------------------
    // wave w writes cols w*64..+63 for all 128 rows (xs region dead now)
    {
        char* zb = (char*)zs;
        #pragma unroll
        for (int nn = 0; nn < 4; ++nn) {
            int colbase = (w * 4 + nn) * 16 + lr;
            float tb = trunk_b[colbase];
            #pragma unroll
            for (int mm = 0; mm < 8; ++mm)
            #pragma unroll
            for (int r = 0; r < 4; ++r) {
                float v = acc[mm][nn][r] + tb;
                v = 0.5f * v * (1.f + erff(v * 0.70710678118654752f));
                int row  = mm * 16 + lg * 4 + r;
                int slot = (colbase >> 3) ^ (row & 7);
                *(ushort*)(zb + row * 512 + slot * 16 + (colbase & 7) * 2) = f2bf(v);
            }
        }
    }
    __syncthreads();   // zs written N-split, read M-split (cross-wave)

    // ---- phase C: head GEMM, M-split: wave w rows w*32..+31, K=256 --------
    const char* zb = (const char*)zs;
    const int p8 = l & 7;
    const int csrc = (l & 48) | (p8 ? (p8 - 1) : 0);
    const int row0 = w * 32 + lr;
    const int row1 = row0 + 16;      // (row1&7)==(row0&7)

    float cw[2][4];
    #pragma unroll
    for (int m = 0; m < 2; ++m)
    #pragma unroll
    for (int r = 0; r < 4; ++r)
        cw[m][r] = __shfl(pwv[m][r], csrc);

    #pragma unroll 1
    for (int hf = 0; hf < 2; ++hf) {
        f32x4 acc2[2][10];
        #pragma unroll
        for (int m = 0; m < 2; ++m)
        #pragma unroll
        for (int n = 0; n < 10; ++n) acc2[m][n] = (f32x4){0.f,0.f,0.f,0.f};
        float wb_[10];
        #pragma unroll
        for (int n = 0; n < 10; ++n) wb_[n] = wbias[(hf * 10 + n) * 16 + lr];

        #pragma unroll
        for (int kk = 0; kk < 8; ++kk) {
            short8 a0 = *(const short8*)(zb + row0 * 512 + (((kk * 4 + lg) ^ (row0 & 7)) << 4));
            short8 a1 = *(const short8*)(zb + row1 * 512 + (((kk * 4 + lg) ^ (row1 & 7)) << 4));
            const ushort* wp = WaP + (size_t)(kk * 20 + hf * 10) * 512;
            #pragma unroll
            for (int n = 0; n < 10; ++n) {
                short8 bq = *(const short8*)(wp + (size_t)n * 512 + l * 8);
                acc2[0][n] = __builtin_amdgcn_mfma_f32_16x16x32_bf16(a0, bq, acc2[0][n],0,0,0);
                acc2[1][n] = __builtin_amdgcn_mfma_f32_16x16x32_bf16(a1, bq, acc2[1][n],0,0,0);
            }
        }

        // ---- phase E: bias, phase-weighted 8-lane reduce, store -----------
        #pragma unroll
        for (int m = 0; m < 2; ++m)
        #pragma unroll
        for (int n = 0; n < 10; ++n)
        #pragma unroll
        for (int r = 0; r < 4; ++r) {
            float e = acc2[m][n][r] + wb_[n];
            float val = (p8 ? cw[m][r] : 1.0f) * e;
            val += __shfl_xor(val, 1);
            val += __shfl_xor(val, 2);
            val += __shfl_xor(val, 4);
            if (p8 == 0) {
                int combo = (hf * 10 + n) * 16 + lr;
                int h = combo / 160, rem = combo % 160, kb = rem >> 3;
                size_t t = block0 + w * 32 + m * 16 + lg * 4 + r;
                out[(size_t)h * (BT * BINS) + t * BINS + kb] = val;
            }
        }
    }
}

// ---------------------------------------------------------------------------
extern "C" void kernel_launch(void* const* d_in, const int* in_sizes, int n_in,
                              void* d_out, int out_size, void* d_ws, size_t ws_size,
                              hipStream_t stream) {
    const float* h_t          = (const float*)d_in[0];
    const float* a_t          = (const float*)d_in[1];
    const float* d_t          = (const float*)d_in[2];
    const float* age_embed    = (const float*)d_in[3];
    const float* trunk_w      = (const float*)d_in[4];
    const float* trunk_b      = (const float*)d_in[5];
    const float* inst_base_w  = (const float*)d_in[6];
    const float* inst_base_b  = (const float*)d_in[7];
    const float* group_base_w = (const float*)d_in[8];
    const float* group_base_b = (const float*)d_in[9];
    const float* inst_exp_w   = (const float*)d_in[10];
    const float* inst_exp_b   = (const float*)d_in[11];
    const float* group_exp_w  = (const float*)d_in[12];
    const float* group_exp_b  = (const float*)d_in[13];
    const float* router_w     = (const float*)d_in[14];
    const float* router_b     = (const float*)d_in[15];

    ushort* WtP   = (ushort*)d_ws;
    ushort* RP    = WtP + WT_P_SZ;
    ushort* WaP   = RP + RP_SZ;
    float*  wbias = (float*)(WaP + WA_P_SZ);

    pack_all<<<481, 64, 0, stream>>>(
        trunk_w, router_w,
        inst_base_w, inst_base_b, group_base_w, group_base_b,
        inst_exp_w, inst_exp_b, group_exp_w, group_exp_b,
        WtP, RP, WaP, wbias);

    fused_mfma<<<BT / 128, 256, 0, stream>>>(
        h_t, a_t, d_t, age_embed, trunk_b, router_b,
        WtP, RP, WaP, wbias, (float*)d_out);
}

// Round 11
// 103.514 us; speedup vs baseline: 1.7635x; 1.0319x over previous
//
#include <hip/hip_runtime.h>
#include <hip/hip_bf16.h>
#include <math.h>

typedef unsigned int uint;
typedef unsigned short ushort;

using short8 = __attribute__((ext_vector_type(8))) short;
using f32x4  = __attribute__((ext_vector_type(4))) float;

#define BT      65536
#define HID     512
#define IN_DIM  594
#define TRUNK   256
#define BINS    20
#define NCOMBO  320

#define WT_P_SZ (19*16*64*8)
#define RP_SZ   (16*64*8)
#define WA_P_SZ (8*20*64*8)

__device__ inline ushort f2bf(float f) {
    uint u = __float_as_uint(f);
    return (ushort)((u + 0x7fffu + ((u >> 16) & 1u)) >> 16);   // RNE
}

// packed f32x2 -> bf16x2; compiler emits v_cvt_pk_bf16_f32 (RNE)
__device__ inline uint pk2(float lo, float hi) {
    union { __hip_bfloat162 b; uint u; } cv;
    cv.b = __float22bfloat162_rn(float2{lo, hi});
    return cv.u;
}
__device__ inline short8 cvt8pk(float4 a, float4 b) {
    union { uint4 t; short8 s; } cv;
    cv.t.x = pk2(a.x, a.y);
    cv.t.y = pk2(a.z, a.w);
    cv.t.z = pk2(b.x, b.y);
    cv.t.w = pk2(b.z, b.w);
    return cv.s;
}

// ---------------------------------------------------------------------------
// Pack weights to bf16 MFMA B-fragment layout (verified R2-R10):
//   frag elem j, lane l, frag (kk,n): B[k][col], k=kk*32+(l>>4)*8+j, col=n*16+(l&15)
// ---------------------------------------------------------------------------
__global__ __launch_bounds__(64) void pack_all(
    const float* __restrict__ trunk_w, const float* __restrict__ router_w,
    const float* __restrict__ inst_base_w, const float* __restrict__ inst_base_b,
    const float* __restrict__ group_base_w, const float* __restrict__ group_base_b,
    const float* __restrict__ inst_exp_w, const float* __restrict__ inst_exp_b,
    const float* __restrict__ group_exp_w, const float* __restrict__ group_exp_b,
    ushort* __restrict__ WtP, ushort* __restrict__ RP,
    ushort* __restrict__ WaP, float* __restrict__ wbias)
{
    const int b = blockIdx.x, l = threadIdx.x;
    const int lr = l & 15, lg = l >> 4;
    if (b < 304) {                      // trunk: kk 0..18, n 0..15
        int kk = b >> 4, n = b & 15;
        int col = n * 16 + lr;
        ushort* dst = WtP + ((size_t)(kk * 16 + n) * 64 + l) * 8;
        #pragma unroll
        for (int j = 0; j < 8; ++j) {
            int k = kk * 32 + lg * 8 + j;
            dst[j] = (k < IN_DIM) ? f2bf(trunk_w[k * TRUNK + col]) : (ushort)0;
        }
    } else if (b < 320) {               // router: kk 0..15
        int kk = b - 304;
        ushort* dst = RP + ((size_t)(kk * 64 + l)) * 8;
        #pragma unroll
        for (int j = 0; j < 8; ++j) {
            int k = kk * 32 + lg * 8 + j;
            dst[j] = (lr < 7) ? f2bf(router_w[k * 7 + lr]) : (ushort)0;
        }
    } else if (b < 480) {               // heads: kk 0..7, n 0..19
        int b2 = b - 320, kk = b2 / 20, n = b2 % 20;
        int combo = n * 16 + lr;
        int h = combo / 160, rem = combo % 160, kb = rem >> 3, p = rem & 7;
        const float* bw = h ? group_base_w : inst_base_w;
        const float* ew = h ? group_exp_w  : inst_exp_w;
        ushort* dst = WaP + ((size_t)(kk * 20 + n) * 64 + l) * 8;
        #pragma unroll
        for (int j = 0; j < 8; ++j) {
            int k = kk * 32 + lg * 8 + j;
            float v = (p == 0) ? bw[k * BINS + kb]
                               : ew[((p - 1) * TRUNK + k) * BINS + kb];
            dst[j] = f2bf(v);
        }
    } else {                            // bias[320]
        for (int c = l; c < NCOMBO; c += 64) {
            int h = c / 160, rem = c % 160, kb = rem >> 3, p = rem & 7;
            const float* bb = h ? group_base_b : inst_base_b;
            const float* eb = h ? group_exp_b  : inst_exp_b;
            wbias[c] = (p == 0) ? bb[kb] : eb[(p - 1) * BINS + kb];
        }
    }
}

// ---------------------------------------------------------------------------
// Fused main (R5 base + packed staging cvt + hybrid phase-C split):
// 128 tokens/block, 4 waves, 512 blocks (2 blocks/CU).
// Phase A: N-split trunk (wave w: N-frags 4w..4w+3, all 8 M-frags), x staged
//          dbuf in A-frag layout with R5's bank-clean (srow,half) map,
//          conversion via v_cvt_pk_bf16_f32; router per-wave rows w*32..+31.
// Phase C: HYBRID split: wave (mw=w>>1, nw=w&1) -> rows mw*64..+63,
//          N-frags nw*10+hf*5..+4 (hf loop) -> head weights read 2x/block
//          (320 KB, half of R5's 640 KB). pw shared via pwl[128][9].
// LDS: zs[128][256] bf16 swizzled (64 KB, xs[2] overlaps) + pwl 4.5 KB.
// ---------------------------------------------------------------------------
__global__ __launch_bounds__(256, 2) void fused_mfma(
    const float* __restrict__ h_t, const float* __restrict__ a_t,
    const float* __restrict__ d_t, const float* __restrict__ age,
    const float* __restrict__ trunk_b, const float* __restrict__ router_b,
    const ushort* __restrict__ WtP, const ushort* __restrict__ RP,
    const ushort* __restrict__ WaP, const float* __restrict__ wbias,
    float* __restrict__ out)
{
    __shared__ alignas(16) ushort zs[32768];   // 64 KB; xs = first 16384 ushorts
    __shared__ float pwl[128 * 9];             // 4.5 KB phase-weight share

    const int tid = threadIdx.x;
    const int l = tid & 63, w = tid >> 6;
    const int lr = l & 15, lg = l >> 4;
    const int block0 = blockIdx.x * 128;

    // staging map (R5, bank-clean): thread -> (row, 16-col half of 32-col chunk)
    const int srow = tid >> 1;
    const int half = tid & 1;
    const size_t stok = block0 + srow;

    ushort* xs = zs;                 // xs[buf][frag mm][lane*8], buf stride 4096

    f32x4 acc[8][4];                          // [M-frag][N-frag] 128 VGPRs
    f32x4 accr0 = (f32x4){0.f,0.f,0.f,0.f};  // router, M-frag 2w
    f32x4 accr1 = (f32x4){0.f,0.f,0.f,0.f};  // router, M-frag 2w+1
    #pragma unroll
    for (int mm = 0; mm < 8; ++mm)
    #pragma unroll
    for (int nn = 0; nn < 4; ++nn) acc[mm][nn] = (f32x4){0.f,0.f,0.f,0.f};

    auto stage_load = [&](int kk, float4 ld[4]) {
        if (kk < 16) {
            const float4* p = (const float4*)(h_t + stok * HID + kk * 32 + half * 16);
            ld[0]=p[0]; ld[1]=p[1]; ld[2]=p[2]; ld[3]=p[3];
        } else if (kk < 18) {
            const float4* p = (const float4*)(a_t + stok * 64 + (kk - 16) * 32 + half * 16);
            ld[0]=p[0]; ld[1]=p[1]; ld[2]=p[2]; ld[3]=p[3];
        } else {
            float* f = (float*)ld;
            #pragma unroll
            for (int j = 0; j < 16; ++j) {
                int c = 576 + half * 16 + j;
                float v;
                if (c < 578)      v = d_t[stok * 2 + (c - 576)];
                else if (c < 594) v = age[stok * 16 + (c - 578)];
                else              v = 0.f;
                f[j] = v;
            }
        }
    };
    auto stage_write = [&](int buf, float4 ld[4]) {
        short8 v0 = cvt8pk(ld[0], ld[1]);
        short8 v1 = cvt8pk(ld[2], ld[3]);
        ushort* dst = xs + buf * 4096 + (srow >> 4) * 512 + ((srow & 15) + half * 32) * 8;
        *(short8*)dst = v0;
        *(short8*)(dst + 128) = v1;    // lane + 16
    };

    // ---- phase A: trunk (K=608, N-split) + router (K=512, per-wave rows) --
    {
        float4 ld[4];
        stage_load(0, ld);
        stage_write(0, ld);
        __syncthreads();
        int cur = 0;
        const int w4 = w * 4;
        #pragma unroll 1
        for (int kk = 0; kk < 19; ++kk) {
            float4 nld[4];
            if (kk < 18) stage_load(kk + 1, nld);

            // B-frags for this wave's N-slice (L2, wave-exclusive)
            const ushort* wp = WtP + ((size_t)kk * 16 + w4) * 512;
            short8 bq0 = *(const short8*)(wp + 0 * 512 + l * 8);
            short8 bq1 = *(const short8*)(wp + 1 * 512 + l * 8);
            short8 bq2 = *(const short8*)(wp + 2 * 512 + l * 8);
            short8 bq3 = *(const short8*)(wp + 3 * 512 + l * 8);

            // A-frags from LDS (lane-linear, conflict-free)
            const ushort* xb = xs + cur * 4096;
            short8 a0 = *(const short8*)(xb + 0 * 512 + l * 8);
            short8 a1 = *(const short8*)(xb + 1 * 512 + l * 8);
            short8 a2 = *(const short8*)(xb + 2 * 512 + l * 8);
            short8 a3 = *(const short8*)(xb + 3 * 512 + l * 8);
            short8 a4 = *(const short8*)(xb + 4 * 512 + l * 8);
            short8 a5 = *(const short8*)(xb + 5 * 512 + l * 8);
            short8 a6 = *(const short8*)(xb + 6 * 512 + l * 8);
            short8 a7 = *(const short8*)(xb + 7 * 512 + l * 8);

            if (kk < 16) {   // router for this wave's head rows (M-frags 2w,2w+1)
                short8 rb = *(const short8*)(RP + (size_t)kk * 512 + l * 8);
                short8 ar0 = *(const short8*)(xb + (w * 2 + 0) * 512 + l * 8);
                short8 ar1 = *(const short8*)(xb + (w * 2 + 1) * 512 + l * 8);
                accr0 = __builtin_amdgcn_mfma_f32_16x16x32_bf16(ar0, rb, accr0, 0, 0, 0);
                accr1 = __builtin_amdgcn_mfma_f32_16x16x32_bf16(ar1, rb, accr1, 0, 0, 0);
            }

            #pragma unroll
            for (int nn = 0; nn < 4; ++nn) {
                short8 bq = (nn == 0) ? bq0 : (nn == 1) ? bq1 : (nn == 2) ? bq2 : bq3;
                acc[0][nn] = __builtin_amdgcn_mfma_f32_16x16x32_bf16(a0, bq, acc[0][nn],0,0,0);
                acc[1][nn] = __builtin_amdgcn_mfma_f32_16x16x32_bf16(a1, bq, acc[1][nn],0,0,0);
                acc[2][nn] = __builtin_amdgcn_mfma_f32_16x16x32_bf16(a2, bq, acc[2][nn],0,0,0);
                acc[3][nn] = __builtin_amdgcn_mfma_f32_16x16x32_bf16(a3, bq, acc[3][nn],0,0,0);
                acc[4][nn] = __builtin_amdgcn_mfma_f32_16x16x32_bf16(a4, bq, acc[4][nn],0,0,0);
                acc[5][nn] = __builtin_amdgcn_mfma_f32_16x16x32_bf16(a5, bq, acc[5][nn],0,0,0);
                acc[6][nn] = __builtin_amdgcn_mfma_f32_16x16x32_bf16(a6, bq, acc[6][nn],0,0,0);
                acc[7][nn] = __builtin_amdgcn_mfma_f32_16x16x32_bf16(a7, bq, acc[7][nn],0,0,0);
            }

            if (kk < 18) stage_write(cur ^ 1, nld);
            __syncthreads();
            cur ^= 1;
        }
    }

    // ---- router softmax (rows w*32..+31) + share pw via pwl ---------------
    {
        const float rb_l = (lr < 7) ? router_b[lr] : 0.f;
        float pwv[2][4];
        #pragma unroll
        for (int m = 0; m < 2; ++m)
        #pragma unroll
        for (int r = 0; r < 4; ++r) {
            float lv = (m == 0) ? accr0[r] : accr1[r];
            float x = (lr < 7) ? (lv + rb_l) : -3.0e38f;
            float mx = x;
            mx = fmaxf(mx, __shfl_xor(mx, 1));
            mx = fmaxf(mx, __shfl_xor(mx, 2));
            mx = fmaxf(mx, __shfl_xor(mx, 4));
            mx = fmaxf(mx, __shfl_xor(mx, 8));
            float e = expf(x - mx);
            float s = e;
            s += __shfl_xor(s, 1);
            s += __shfl_xor(s, 2);
            s += __shfl_xor(s, 4);
            s += __shfl_xor(s, 8);
            pwv[m][r] = e / s;
        }
        if (lr < 7) {
            #pragma unroll
            for (int m = 0; m < 2; ++m)
            #pragma unroll
            for (int r = 0; r < 4; ++r)
                pwl[(w * 32 + m * 16 + lg * 4 + r) * 9 + lr] = pwv[m][r];
        }
    }

    // ---- epilogue: bias + exact GELU -> swizzled bf16 zs ------------------
    // wave w writes cols w*64..+63 for all 128 rows (xs region dead now)
    {
        char* zb = (char*)zs;
        #pragma unroll
        for (int nn = 0; nn < 4; ++nn) {
            int colbase = (w * 4 + nn) * 16 + lr;
            float tb = trunk_b[colbase];
            #pragma unroll
            for (int mm = 0; mm < 8; ++mm)
            #pragma unroll
            for (int r = 0; r < 4; ++r) {
                float v = acc[mm][nn][r] + tb;
                v = 0.5f * v * (1.f + erff(v * 0.70710678118654752f));
                int row  = mm * 16 + lg * 4 + r;
                int slot = (colbase >> 3) ^ (row & 7);
                *(ushort*)(zb + row * 512 + slot * 16 + (colbase & 7) * 2) = f2bf(v);
            }
        }
    }
    __syncthreads();   // zs + pwl cross-wave visibility

    // ---- phase C: head GEMM, HYBRID split: wave (mw,nw) -------------------
    //   rows mw*64..+63 (M-frags 4mw..4mw+3), N-frags nw*10+hf*5..+4
    const char* zb = (const char*)zs;
    const int mw = w >> 1;
    const int nw = w & 1;
    const int p8 = l & 7;
    const int psel = p8 ? (p8 - 1) : 0;

    float cwv[4][4];
    #pragma unroll
    for (int mm = 0; mm < 4; ++mm)
    #pragma unroll
    for (int r = 0; r < 4; ++r)
        cwv[mm][r] = pwl[(mw * 64 + mm * 16 + lg * 4 + r) * 9 + psel];

    #pragma unroll 1
    for (int hf = 0; hf < 2; ++hf) {
        const int nbase = nw * 10 + hf * 5;
        f32x4 acc2[4][5];
        #pragma unroll
        for (int mm = 0; mm < 4; ++mm)
        #pragma unroll
        for (int n = 0; n < 5; ++n) acc2[mm][n] = (f32x4){0.f,0.f,0.f,0.f};
        float wb_[5];
        #pragma unroll
        for (int n = 0; n < 5; ++n) wb_[n] = wbias[(nbase + n) * 16 + lr];

        #pragma unroll
        for (int kk = 0; kk < 8; ++kk) {
            short8 a[4];
            #pragma unroll
            for (int mm = 0; mm < 4; ++mm) {
                int row = mw * 64 + mm * 16 + lr;
                a[mm] = *(const short8*)(zb + row * 512 + (((kk * 4 + lg) ^ (row & 7)) << 4));
            }
            const ushort* wp = WaP + ((size_t)kk * 20 + nbase) * 512;
            #pragma unroll
            for (int n = 0; n < 5; ++n) {
                short8 bq = *(const short8*)(wp + (size_t)n * 512 + l * 8);
                acc2[0][n] = __builtin_amdgcn_mfma_f32_16x16x32_bf16(a[0], bq, acc2[0][n],0,0,0);
                acc2[1][n] = __builtin_amdgcn_mfma_f32_16x16x32_bf16(a[1], bq, acc2[1][n],0,0,0);
                acc2[2][n] = __builtin_amdgcn_mfma_f32_16x16x32_bf16(a[2], bq, acc2[2][n],0,0,0);
                acc2[3][n] = __builtin_amdgcn_mfma_f32_16x16x32_bf16(a[3], bq, acc2[3][n],0,0,0);
            }
        }

        // ---- phase E: bias, phase-weighted 8-lane reduce, store -----------
        #pragma unroll
        for (int n = 0; n < 5; ++n) {
            int combo = (nbase + n) * 16 + lr;
            int h = combo / 160, rem = combo % 160, kb = rem >> 3;
            #pragma unroll
            for (int mm = 0; mm < 4; ++mm)
            #pragma unroll
            for (int r = 0; r < 4; ++r) {
                float e = acc2[mm][n][r] + wb_[n];
                float val = (p8 ? cwv[mm][r] : 1.0f) * e;
                val += __shfl_xor(val, 1);
                val += __shfl_xor(val, 2);
                val += __shfl_xor(val, 4);
                if (p8 == 0) {
                    size_t t = block0 + mw * 64 + mm * 16 + lg * 4 + r;
                    out[(size_t)h * (BT * BINS) + t * BINS + kb] = val;
                }
            }
        }
    }
}

// ---------------------------------------------------------------------------
extern "C" void kernel_launch(void* const* d_in, const int* in_sizes, int n_in,
                              void* d_out, int out_size, void* d_ws, size_t ws_size,
                              hipStream_t stream) {
    const float* h_t          = (const float*)d_in[0];
    const float* a_t          = (const float*)d_in[1];
    const float* d_t          = (const float*)d_in[2];
    const float* age_embed    = (const float*)d_in[3];
    const float* trunk_w      = (const float*)d_in[4];
    const float* trunk_b      = (const float*)d_in[5];
    const float* inst_base_w  = (const float*)d_in[6];
    const float* inst_base_b  = (const float*)d_in[7];
    const float* group_base_w = (const float*)d_in[8];
    const float* group_base_b = (const float*)d_in[9];
    const float* inst_exp_w   = (const float*)d_in[10];
    const float* inst_exp_b   = (const float*)d_in[11];
    const float* group_exp_w  = (const float*)d_in[12];
    const float* group_exp_b  = (const float*)d_in[13];
    const float* router_w     = (const float*)d_in[14];
    const float* router_b     = (const float*)d_in[15];

    ushort* WtP   = (ushort*)d_ws;
    ushort* RP    = WtP + WT_P_SZ;
    ushort* WaP   = RP + RP_SZ;
    float*  wbias = (float*)(WaP + WA_P_SZ);

    pack_all<<<481, 64, 0, stream>>>(
        trunk_w, router_w,
        inst_base_w, inst_base_b, group_base_w, group_base_b,
        inst_exp_w, inst_exp_b, group_exp_w, group_exp_b,
        WtP, RP, WaP, wbias);

    fused_mfma<<<BT / 128, 256, 0, stream>>>(
        h_t, a_t, d_t, age_embed, trunk_b, router_b,
        WtP, RP, WaP, wbias, (float*)d_out);
}